// Round 2
// baseline (288.913 us; speedup 1.0000x reference)
//
#include <hip/hip_runtime.h>

// SpectralPooling: x (4,64,64,64,32) f32 -> out (4,32,32,32,32) f32.
// DCT64 -> trunc 24 -> pad 32 -> iDCT32 per axis collapses to one 32x64 matrix A.
//   k0: compute A (32x64)
//   k1: y1[b][p][hwc]  = A @ x[b][d][hwc]     (batch 4,   S2=65536 float2)
//   k2: y2[bp][q][wc]  = A @ y1[bp][h][wc]    (batch 128, S2=1024 float2)
//   k3: out[b][r][q][p][c] = sum_w A[r][w] y2[b][p][q][w][c]  (+transpose)
// Round 2: hand-pipelined 8-deep load double-buffer in all reduction loops
// (round-1 was latency-bound: ~1 load in flight -> 1.6 TB/s, VALUBusy 21%).

#define PI_D 3.14159265358979323846

__global__ __launch_bounds__(256) void sp_compute_A(float* __restrict__ A) {
    int idx = blockIdx.x * 256 + threadIdx.x;   // 0..2047
    if (idx >= 2048) return;
    int o = idx >> 6;   // 0..31 (output index)
    int i = idx & 63;   // 0..63 (input index)
    double acc = 0.0;
    for (int p = 0; p < 24; ++p) {
        double s32 = (p == 0) ? sqrt(1.0 / 32.0) : sqrt(2.0 / 32.0);
        double s64 = (p == 0) ? sqrt(1.0 / 64.0) : sqrt(2.0 / 64.0);
        acc += s32 * cos(PI_D * (o + 0.5) * p / 32.0)
             * s64 * cos(PI_D * (i + 0.5) * p / 64.0);
    }
    A[idx] = (float)acc;
}

// Y[b][p][n] = sum_k A[p][k] * X[b][k][n]   (p=0..31, k=0..63), n as float2.
// S2 = compile-time float2 stride between consecutive k rows.
template<int S2>
__global__ __launch_bounds__(256, 3) void sp_contract(
        const float* __restrict__ X, const float* __restrict__ Amat,
        float* __restrict__ Y) {
    __shared__ float As[64][32];           // As[k][p] = A[p][k]
    int t = threadIdx.x;
    for (int i = t; i < 2048; i += 256) {
        int p = i >> 6, k = i & 63;
        As[k][p] = Amat[i];
    }
    __syncthreads();

    long b  = blockIdx.y;
    long n2 = (long)blockIdx.x * 256 + t;  // float2 index within batch row

    const float2* xp = (const float2*)X + b * 64 * (long)S2 + n2;

    float2 acc[32];
#pragma unroll
    for (int p = 0; p < 32; ++p) acc[p] = make_float2(0.f, 0.f);

    float2 bufA[8], bufB[8];
#pragma unroll
    for (int u = 0; u < 8; ++u) bufA[u] = xp[(long)u * S2];

#pragma unroll
    for (int kg = 0; kg < 8; ++kg) {
        if (kg < 7) {
#pragma unroll
            for (int u = 0; u < 8; ++u) bufB[u] = xp[(long)(kg * 8 + 8 + u) * S2];
        }
#pragma unroll
        for (int u = 0; u < 8; ++u) {
            int k = kg * 8 + u;
            float2 xv = bufA[u];
            const float4* Arow = (const float4*)&As[k][0];
#pragma unroll
            for (int pg = 0; pg < 8; ++pg) {
                float4 a4 = Arow[pg];
                acc[pg * 4 + 0].x += a4.x * xv.x; acc[pg * 4 + 0].y += a4.x * xv.y;
                acc[pg * 4 + 1].x += a4.y * xv.x; acc[pg * 4 + 1].y += a4.y * xv.y;
                acc[pg * 4 + 2].x += a4.z * xv.x; acc[pg * 4 + 2].y += a4.z * xv.y;
                acc[pg * 4 + 3].x += a4.w * xv.x; acc[pg * 4 + 3].y += a4.w * xv.y;
            }
        }
#pragma unroll
        for (int u = 0; u < 8; ++u) bufA[u] = bufB[u];
    }

    float2* yp = (float2*)Y + b * 32 * (long)S2 + n2;
#pragma unroll
    for (int p = 0; p < 32; ++p) yp[(long)p * S2] = acc[p];
}

// out[b][r][q][p][c] = sum_w A[r][w] * y2[b][p][q][w][c]
// j = ((b*32+p)*32+q); 16 j's per block, thread = (j_local, c2) with float2 c.
__global__ __launch_bounds__(256, 3) void sp_contract_w_transpose(
        const float* __restrict__ Y2, const float* __restrict__ Amat,
        float* __restrict__ Out) {
    __shared__ float As[64][32];           // As[w][r] = A[r][w]
    int t = threadIdx.x;
    for (int i = t; i < 2048; i += 256) {
        int r = i >> 6, w = i & 63;
        As[w][r] = Amat[i];
    }
    __syncthreads();

    int j  = blockIdx.x * 16 + (t >> 4);   // (b,p,q) flat index
    int c2 = t & 15;                       // float2 channel index
    int b = j >> 10;
    int p = (j >> 5) & 31;
    int q = j & 31;

    const float2* src = (const float2*)Y2 + (long)j * 1024 + c2;  // w-stride 16

    float2 acc[32];
#pragma unroll
    for (int r = 0; r < 32; ++r) acc[r] = make_float2(0.f, 0.f);

    float2 bufA[8], bufB[8];
#pragma unroll
    for (int u = 0; u < 8; ++u) bufA[u] = src[u * 16];

#pragma unroll
    for (int wg = 0; wg < 8; ++wg) {
        if (wg < 7) {
#pragma unroll
            for (int u = 0; u < 8; ++u) bufB[u] = src[(wg * 8 + 8 + u) * 16];
        }
#pragma unroll
        for (int u = 0; u < 8; ++u) {
            int w = wg * 8 + u;
            float2 xv = bufA[u];
            const float4* Arow = (const float4*)&As[w][0];
#pragma unroll
            for (int rg = 0; rg < 8; ++rg) {
                float4 a4 = Arow[rg];
                acc[rg * 4 + 0].x += a4.x * xv.x; acc[rg * 4 + 0].y += a4.x * xv.y;
                acc[rg * 4 + 1].x += a4.y * xv.x; acc[rg * 4 + 1].y += a4.y * xv.y;
                acc[rg * 4 + 2].x += a4.z * xv.x; acc[rg * 4 + 2].y += a4.z * xv.y;
                acc[rg * 4 + 3].x += a4.w * xv.x; acc[rg * 4 + 3].y += a4.w * xv.y;
            }
        }
#pragma unroll
        for (int u = 0; u < 8; ++u) bufA[u] = bufB[u];
    }

    // out flat: b*1048576 + r*32768 + q*1024 + p*32 + c   (float2: /2)
    float2* dst = (float2*)Out + (long)b * 524288 + (long)q * 512 + p * 16 + c2;
#pragma unroll
    for (int r = 0; r < 32; ++r) dst[(long)r * 16384] = acc[r];
}

extern "C" void kernel_launch(void* const* d_in, const int* in_sizes, int n_in,
                              void* d_out, int out_size, void* d_ws, size_t ws_size,
                              hipStream_t stream) {
    const float* x = (const float*)d_in[0];         // 4*64*64*64*32 f32
    float* out = (float*)d_out;                     // 4*32*32*32*32 f32

    float* A  = (float*)d_ws;                       // 2048 floats
    float* y1 = A + 2048;                           // 16,777,216 f32 (64 MiB)
    float* y2 = y1 + 16777216;                      // 8,388,608 f32 (32 MiB)

    sp_compute_A<<<8, 256, 0, stream>>>(A);

    // k1: contract D.  batch=4, rows 64 x 65536 float2
    sp_contract<65536><<<dim3(256, 4), 256, 0, stream>>>(x, A, y1);

    // k2: contract H.  batch=128, rows 64 x 1024 float2
    sp_contract<1024><<<dim3(4, 128), 256, 0, stream>>>(y1, A, y2);

    // k3: contract W + transposed writeout. 4096 j / 16 per block
    sp_contract_w_transpose<<<256, 256, 0, stream>>>(y2, A, out);
}

// Round 4
// 253.446 us; speedup vs baseline: 1.1399x; 1.1399x over previous
//
#include <hip/hip_runtime.h>

// SpectralPooling: x (4,64,64,64,32) f32 -> out (4,32,32,32,32) f32.
// DCT64 -> trunc 24 -> pad 32 -> iDCT32 per axis == one 32x64 matrix A, same
// for all axes, and the three axis contractions commute. Round 3: contract
// W first so the big 128-MiB pass is fully-contiguous, and use one generic
// LDS-staged tile kernel for all three passes:
//   tile = [64 rows (reduction axis, stride KS) x 128 B contiguous]
//   staged per-wave via 8x global_load_lds dwordx4 (16 B/lane, full lines)
//   compute: lane=(j2,og): acc[8 o] x float2; 16 FMA + broadcast LDS reads /k
//   store: [32 o x 128 B] tile, stride OS (contiguous 4 KB for P1/P3)
// P1: contract w: x[t=b*d*h][64 w][32 c]        -> y1[t][32 r][32 c]
// P2: contract h: y1[bd][64 h][1024 rc]         -> y2[bd][32 q][1024 rc]
// P3: contract d: y2[b][64 d][q][r][c] (+transpose) -> out[b][r][q][32 d'][c]
// ws: A 8 KB | y1 64 MiB | y2 32 MiB

#define PI_D 3.14159265358979323846

__global__ __launch_bounds__(256) void sp_compute_A(float* __restrict__ A) {
    int idx = blockIdx.x * 256 + threadIdx.x;   // 0..2047
    if (idx >= 2048) return;
    int o = idx >> 6;   // 0..31 (output index)
    int i = idx & 63;   // 0..63 (input index)
    double acc = 0.0;
    for (int p = 0; p < 24; ++p) {
        double s32 = (p == 0) ? sqrt(1.0 / 32.0) : sqrt(2.0 / 32.0);
        double s64 = (p == 0) ? sqrt(1.0 / 64.0) : sqrt(2.0 / 64.0);
        acc += s32 * cos(PI_D * (o + 0.5) * p / 32.0)
             * s64 * cos(PI_D * (i + 0.5) * p / 64.0);
    }
    A[idx] = (float)acc;   // A[o][i], row-major 32x64
}

template<int PASS>
__global__ __launch_bounds__(256) void sp_pass(const float* __restrict__ X,
                                               const float* __restrict__ Amat,
                                               float* __restrict__ Y) {
    __shared__ float As[2048];        // As[k*32+o] = A[o][k]
    __shared__ float tiles[4][2048];  // per-wave tile: [64 rows][32 floats]

    int t = threadIdx.x;
    // Load A transposed; consecutive lanes -> consecutive LDS addrs (no conflict)
    for (int i = t; i < 2048; i += 256) {
        int k = i >> 5, o = i & 31;
        As[i] = Amat[o * 64 + k];
    }
    __syncthreads();

    int wave = t >> 6, lane = t & 63;
    long tile = (long)blockIdx.x * 4 + wave;

    constexpr int KS = (PASS == 1) ? 32 : (PASS == 2) ? 1024 : 32768;  // row stride in, floats
    constexpr int OS = (PASS == 1) ? 32 : (PASS == 2) ? 1024 : 32;     // row stride out, floats

    long in_base, out_base;
    if constexpr (PASS == 1) {
        in_base  = tile * 2048;            // x: [16384][64 w][32 c]
        out_base = tile * 1024;            // y1: [16384][32 r][32 c]
    } else if constexpr (PASS == 2) {
        long bd = tile >> 5; int jt = (int)tile & 31;
        in_base  = bd * 65536 + jt * 32;   // y1: [256 bd][64 h][1024 rc]
        out_base = bd * 32768 + jt * 32;   // y2: [256 bd][32 q][1024 rc]
    } else {
        long b = tile >> 10; int q = ((int)tile >> 5) & 31, r = (int)tile & 31;
        in_base  = b * 2097152 + q * 1024 + r * 32;   // y2: [4 b][64 d][32 q][32 r][32 c]
        out_base = b * 1048576 + r * 32768 + q * 1024; // out: [4 b][32 r][32 q][32 d'][32 c]
    }

    // ---- stage [64][128 B] tile into LDS: 8 instrs x (64 lanes x 16 B) ----
    float* ltile = &tiles[wave][0];
    const float* gsrc = X + in_base + (long)(lane >> 3) * KS + (lane & 7) * 4;
#pragma unroll
    for (int i = 0; i < 8; ++i) {
        __builtin_amdgcn_global_load_lds(
            (const __attribute__((address_space(1))) void*)(gsrc + (long)i * 8 * KS),
            (__attribute__((address_space(3))) void*)(ltile + i * 256),
            16, 0, 0);
    }
    asm volatile("s_waitcnt vmcnt(0)" ::: "memory");
    __builtin_amdgcn_sched_barrier(0);

    // ---- compute: thread = (j2 = lane&15 float2-col, og = lane>>4 o-group) ----
    int j2 = lane & 15, og = lane >> 4;
    const float2* xs  = (const float2*)ltile + j2;   // + k*16
    const float4* as4 = (const float4*)As + og * 2;  // + k*8 (two float4 per k)

    float2 acc[8];
#pragma unroll
    for (int i = 0; i < 8; ++i) acc[i] = make_float2(0.f, 0.f);

#pragma unroll
    for (int k = 0; k < 64; ++k) {
        float2 xv = xs[k * 16];
        float4 a0 = as4[k * 8];
        float4 a1 = as4[k * 8 + 1];
        acc[0].x += a0.x * xv.x; acc[0].y += a0.x * xv.y;
        acc[1].x += a0.y * xv.x; acc[1].y += a0.y * xv.y;
        acc[2].x += a0.z * xv.x; acc[2].y += a0.z * xv.y;
        acc[3].x += a0.w * xv.x; acc[3].y += a0.w * xv.y;
        acc[4].x += a1.x * xv.x; acc[4].y += a1.x * xv.y;
        acc[5].x += a1.y * xv.x; acc[5].y += a1.y * xv.y;
        acc[6].x += a1.z * xv.x; acc[6].y += a1.z * xv.y;
        acc[7].x += a1.w * xv.x; acc[7].y += a1.w * xv.y;
    }

    // ---- store [32 o][128 B] tile, row stride OS ----
    float2* dst = (float2*)(Y + out_base) + j2;
#pragma unroll
    for (int i = 0; i < 8; ++i) {
        int o = og * 8 + i;
        dst[(long)o * (OS / 2)] = acc[i];
    }
}

extern "C" void kernel_launch(void* const* d_in, const int* in_sizes, int n_in,
                              void* d_out, int out_size, void* d_ws, size_t ws_size,
                              hipStream_t stream) {
    const float* x = (const float*)d_in[0];         // 4*64*64*64*32 f32
    float* out = (float*)d_out;                     // 4*32*32*32*32 f32

    float* A  = (float*)d_ws;                       // 2048 floats
    float* y1 = A + 2048;                           // 16,777,216 f32 (64 MiB)
    float* y2 = y1 + 16777216;                      // 8,388,608 f32 (32 MiB)

    sp_compute_A<<<8, 256, 0, stream>>>(A);

    // P1: 16384 tiles, 4 waves/block -> 4096 blocks (contiguous streaming read of x)
    sp_pass<1><<<4096, 256, 0, stream>>>(x, A, y1);

    // P2: 256 bd * 32 jt = 8192 tiles -> 2048 blocks
    sp_pass<2><<<2048, 256, 0, stream>>>(y1, A, y2);

    // P3: 4 b * 32 q * 32 r = 4096 tiles -> 1024 blocks (does the output transpose)
    sp_pass<3><<<1024, 256, 0, stream>>>(y2, A, out);
}